// Round 11
// baseline (51.287 us; speedup 1.0000x reference)
//
#include <hip/hip_runtime.h>
#include <hip/hip_bf16.h>

typedef __bf16 bf16x8 __attribute__((ext_vector_type(8)));
typedef float  f32x4  __attribute__((ext_vector_type(4)));

#define NTILES 16384               // 262144 rows / 16

// ---------------------------------------------------------------------------
// Kernel 1 (one-shot): expand quaternion weight (32,32,4) -> W_eff (128x128)
// bf16, MFMA A-fragment order, k-axis PERMUTED for full-granule direct loads
// (verbatim r4/r5/r10, HW-verified):
//   element j of fragment (nt,kb,lane) holds physical
//     k = kb*32 + (j<4 ? g*4+j : 16 + g*4 + (j-4)),  g = lane>>4
// ---------------------------------------------------------------------------
__global__ __launch_bounds__(256) void prep_wfrag(const float* __restrict__ w,
                                                  ushort* __restrict__ wfrag) {
    int t = blockIdx.x * 256 + threadIdx.x;
    if (t >= 128 * 128) return;
    int j    = t & 7;
    int lane = (t >> 3) & 63;
    int kb   = (t >> 9) & 3;
    int nt   = t >> 11;
    int g    = lane >> 4;
    int n = nt * 16 + (lane & 15);
    int k = kb * 32 + (j < 4 ? g * 4 + j : 16 + g * 4 + (j - 4));
    int o  = n >> 2, c = n & 3;
    int nq = k >> 2, d = k & 3;
    int comp = c ^ d;                   // Hamilton tables (verified r1-r10)
    bool neg = (d != 0) && ((c == 0) || (c != d && d != (c % 3) + 1));
    float val = w[o * 128 + nq * 4 + comp];
    val = neg ? -val : val;
    __bf16 bv = (__bf16)val;
    wfrag[t] = *reinterpret_cast<ushort*>(&bv);
}

// ---------------------------------------------------------------------------
// Kernel 2: out = x @ W_eff^T + bias.  2 ADJACENT tiles per wave with a FUSED
// MFMA loop: each W fragment is ds_read once and feeds both tiles' MFMAs
// (halves the dominant 537MB LDS W-read stream).  r10's staged full-line
// non-temporal store path retained verbatim.
// ---------------------------------------------------------------------------
__global__ __launch_bounds__(256, 4) void qgemm(const float* __restrict__ x,
                                                const ushort* __restrict__ wfrag,
                                                const float* __restrict__ bias,
                                                float* __restrict__ out) {
    __shared__ __align__(16) ushort wlds[16384];   // 32 KB: W fragments, later store stage
    __shared__ __align__(16) float  sbias[128];

    int tid   = threadIdx.x;
    int lane  = tid & 63;
    int wid   = tid >> 6;      // 0..3
    int row16 = lane & 15;
    int kgrp  = lane >> 4;     // 0..3
    int loff  = row16 * 128 + kgrp * 4;

    // 1) W-copy loads first (x loads stay in flight through the ds_write wait)
    int4 wtmp[8];
    {
        const int4* src = (const int4*)wfrag;
#pragma unroll
        for (int i = 0; i < 8; ++i) wtmp[i] = src[tid + i * 256];
    }

    // 2) x loads for BOTH adjacent tiles (16 x dwordx4, granule-clean)
    size_t t0 = ((size_t)blockIdx.x * 4 + wid) * 2;    // tiles t0, t0+1
    const float4* xv = (const float4*)(x + t0 * 2048 + loff);
    float4 rA[8], rB[8];
#pragma unroll
    for (int kb = 0; kb < 4; ++kb) {
        rA[2 * kb]     = xv[kb * 8];
        rA[2 * kb + 1] = xv[kb * 8 + 4];
    }
#pragma unroll
    for (int kb = 0; kb < 4; ++kb) {
        rB[2 * kb]     = xv[512 + kb * 8];
        rB[2 * kb + 1] = xv[512 + kb * 8 + 4];
    }

    // 3) W -> LDS, bias -> LDS, barrier
    {
        int4* dst = (int4*)wlds;
#pragma unroll
        for (int i = 0; i < 8; ++i) dst[tid + i * 256] = wtmp[i];
    }
    if (tid < 128) sbias[tid] = bias[tid];
    __syncthreads();

    // 4) cvt both tiles -> bf16 fragments
    bf16x8 afrA[4], afrB[4];
#pragma unroll
    for (int kb = 0; kb < 4; ++kb) {
        float4 p = rA[2 * kb], q = rA[2 * kb + 1];
        afrA[kb][0] = (__bf16)p.x; afrA[kb][1] = (__bf16)p.y;
        afrA[kb][2] = (__bf16)p.z; afrA[kb][3] = (__bf16)p.w;
        afrA[kb][4] = (__bf16)q.x; afrA[kb][5] = (__bf16)q.y;
        afrA[kb][6] = (__bf16)q.z; afrA[kb][7] = (__bf16)q.w;
    }
#pragma unroll
    for (int kb = 0; kb < 4; ++kb) {
        float4 p = rB[2 * kb], q = rB[2 * kb + 1];
        afrB[kb][0] = (__bf16)p.x; afrB[kb][1] = (__bf16)p.y;
        afrB[kb][2] = (__bf16)p.z; afrB[kb][3] = (__bf16)p.w;
        afrB[kb][4] = (__bf16)q.x; afrB[kb][5] = (__bf16)q.y;
        afrB[kb][6] = (__bf16)q.z; afrB[kb][7] = (__bf16)q.w;
    }

    // 5) FUSED MFMA: each W fragment read once, feeds both tiles.
    const bf16x8* blds = (const bf16x8*)wlds;
    f32x4 accA[8], accB[8];
#pragma unroll
    for (int nt = 0; nt < 8; ++nt) {
        f32x4 b0 = *(const f32x4*)&sbias[nt * 16 + kgrp * 4];
        accA[nt] = b0;
        accB[nt] = b0;
#pragma unroll
        for (int kb = 0; kb < 4; ++kb) {
            bf16x8 wfr = blds[(nt * 4 + kb) * 64 + lane];
            accA[nt] = __builtin_amdgcn_mfma_f32_16x16x32_bf16(wfr, afrA[kb], accA[nt], 0, 0, 0);
            accB[nt] = __builtin_amdgcn_mfma_f32_16x16x32_bf16(wfr, afrB[kb], accB[nt], 0, 0, 0);
        }
    }

    // 6) all waves done reading W -> wlds reusable as store stage
    __syncthreads();

    // 7+8) per tile: stage acc (XOR-swizzled, full-wave) -> fence ->
    //      8 x 1KB-contiguous non-temporal stores (full 128B lines).
    float* stg = (float*)wlds + wid * 2048;
#pragma unroll
    for (int nt = 0; nt < 8; ++nt) {
        int c = nt * 4 + kgrp;
        *(f32x4*)(stg + row16 * 128 + ((c ^ (row16 & 7)) << 2)) = accA[nt];
    }
    asm volatile("s_waitcnt lgkmcnt(0)" ::: "memory");
    __builtin_amdgcn_sched_barrier(0);
    f32x4* ob = (f32x4*)(out + t0 * 2048);
#pragma unroll
    for (int s = 0; s < 8; ++s) {
        int p   = lane + 64 * s;
        int row = p >> 5;
        int c   = p & 31;
        f32x4 v = *(const f32x4*)(stg + row * 128 + ((c ^ (row & 7)) << 2));
        __builtin_nontemporal_store(v, ob + p);
    }
    // tile 1: same-wave DS ordering; reads above have drained into the VMEM
    // pipe (register deps satisfied) before these writes land.
#pragma unroll
    for (int nt = 0; nt < 8; ++nt) {
        int c = nt * 4 + kgrp;
        *(f32x4*)(stg + row16 * 128 + ((c ^ (row16 & 7)) << 2)) = accB[nt];
    }
    asm volatile("s_waitcnt lgkmcnt(0)" ::: "memory");
    __builtin_amdgcn_sched_barrier(0);
#pragma unroll
    for (int s = 0; s < 8; ++s) {
        int p   = lane + 64 * s;
        int row = p >> 5;
        int c   = p & 31;
        f32x4 v = *(const f32x4*)(stg + row * 128 + ((c ^ (row & 7)) << 2));
        __builtin_nontemporal_store(v, ob + 512 + p);
    }
}

extern "C" void kernel_launch(void* const* d_in, const int* in_sizes, int n_in,
                              void* d_out, int out_size, void* d_ws, size_t ws_size,
                              hipStream_t stream) {
    const float* x      = (const float*)d_in[0];   // [262144,128] fp32
    const float* weight = (const float*)d_in[1];   // [32,32,4] fp32
    const float* bias   = (const float*)d_in[2];   // [128] fp32
    float*       out    = (float*)d_out;           // [262144,128] fp32
    ushort*      wfrag  = (ushort*)d_ws;           // 32 KB fragment-ordered W_eff

    prep_wfrag<<<64, 256, 0, stream>>>(weight, wfrag);
    qgemm<<<2048, 256, 0, stream>>>(x, wfrag, bias, out);
}

// Round 12
// 50.064 us; speedup vs baseline: 1.0244x; 1.0244x over previous
//
#include <hip/hip_runtime.h>
#include <hip/hip_bf16.h>

typedef __bf16 bf16x8 __attribute__((ext_vector_type(8)));
typedef float  f32x4  __attribute__((ext_vector_type(4)));

#define NTILES 16384               // 262144 rows / 16

// ---------------------------------------------------------------------------
// Kernel 1 (one-shot): expand quaternion weight (32,32,4) -> W_eff (128x128)
// bf16, MFMA A-fragment order, k-axis PERMUTED for full-granule direct loads
// (verbatim r4/r5/r10, HW-verified):
//   element j of fragment (nt,kb,lane) holds physical
//     k = kb*32 + (j<4 ? g*4+j : 16 + g*4 + (j-4)),  g = lane>>4
// ---------------------------------------------------------------------------
__global__ __launch_bounds__(256) void prep_wfrag(const float* __restrict__ w,
                                                  ushort* __restrict__ wfrag) {
    int t = blockIdx.x * 256 + threadIdx.x;
    if (t >= 128 * 128) return;
    int j    = t & 7;
    int lane = (t >> 3) & 63;
    int kb   = (t >> 9) & 3;
    int nt   = t >> 11;
    int g    = lane >> 4;
    int n = nt * 16 + (lane & 15);
    int k = kb * 32 + (j < 4 ? g * 4 + j : 16 + g * 4 + (j - 4));
    int o  = n >> 2, c = n & 3;
    int nq = k >> 2, d = k & 3;
    int comp = c ^ d;                   // Hamilton tables (verified r1-r11)
    bool neg = (d != 0) && ((c == 0) || (c != d && d != (c % 3) + 1));
    float val = w[o * 128 + nq * 4 + comp];
    val = neg ? -val : val;
    __bf16 bv = (__bf16)val;
    wfrag[t] = *reinterpret_cast<ushort*>(&bv);
}

// ---------------------------------------------------------------------------
// Kernel 2: out = x @ W_eff^T + bias.  r10 math verbatim, repacked as
// 512-thread blocks (8 waves) under a 64-reg budget -> 4 blocks/CU x 8 waves
// = 32 waves/CU (2x r10's occupancy).  Store path = feature-half staging:
// per wave, stage chunks 0-15 into a 4KB slice of wlds (slot = (c&15) ^
// (row&7), bank-uniform), store 4 instrs x (4 rows x 256B full lines),
// then chunks 16-31.  Explicit lgkmcnt fences on every LDS write->read edge.
// ---------------------------------------------------------------------------
__global__ __launch_bounds__(512, 8) void qgemm(const float* __restrict__ x,
                                                const ushort* __restrict__ wfrag,
                                                const float* __restrict__ bias,
                                                float* __restrict__ out) {
    __shared__ __align__(16) ushort wlds[16384];   // 32 KB: W fragments, later 8x4KB store stage
    __shared__ __align__(16) float  sbias[128];

    int tid   = threadIdx.x;
    int lane  = tid & 63;
    int wid   = tid >> 6;      // 0..7
    int row16 = lane & 15;
    int kgrp  = lane >> 4;     // 0..3
    int loff  = row16 * 128 + kgrp * 4;

    // 1) x loads first (8 x dwordx4, granule-clean via k-permutation)
    size_t tile = (size_t)blockIdx.x * 8 + wid;    // 0..16383
    const float4* xv = (const float4*)(x + tile * 2048 + loff);
    float4 r[8];
#pragma unroll
    for (int kb = 0; kb < 4; ++kb) {
        r[2 * kb]     = xv[kb * 8];
        r[2 * kb + 1] = xv[kb * 8 + 4];
    }

    // 2) W -> LDS (32 KB / 512 threads = 4 int4 each), bias -> LDS, barrier
    int4 wtmp[4];
    {
        const int4* src = (const int4*)wfrag;
#pragma unroll
        for (int i = 0; i < 4; ++i) wtmp[i] = src[tid + i * 512];
        int4* dst = (int4*)wlds;
#pragma unroll
        for (int i = 0; i < 4; ++i) dst[tid + i * 512] = wtmp[i];
    }
    if (tid < 128) sbias[tid] = bias[tid];
    __syncthreads();

    // 3) cvt x -> bf16 fragments
    bf16x8 afr[4];
#pragma unroll
    for (int kb = 0; kb < 4; ++kb) {
        float4 p = r[2 * kb], q = r[2 * kb + 1];
        afr[kb][0] = (__bf16)p.x; afr[kb][1] = (__bf16)p.y;
        afr[kb][2] = (__bf16)p.z; afr[kb][3] = (__bf16)p.w;
        afr[kb][4] = (__bf16)q.x; afr[kb][5] = (__bf16)q.y;
        afr[kb][6] = (__bf16)q.z; afr[kb][7] = (__bf16)q.w;
    }

    // 4) MFMA: acc[nt] = features nt*16+kgrp*4..+3 of batch row row16 (+bias)
    const bf16x8* blds = (const bf16x8*)wlds;
    f32x4 acc[8];
#pragma unroll
    for (int nt = 0; nt < 8; ++nt) {
        acc[nt] = *(const f32x4*)&sbias[nt * 16 + kgrp * 4];
#pragma unroll
        for (int kb = 0; kb < 4; ++kb) {
            bf16x8 wfr = blds[(nt * 4 + kb) * 64 + lane];
            acc[nt] = __builtin_amdgcn_mfma_f32_16x16x32_bf16(wfr, afr[kb], acc[nt], 0, 0, 0);
        }
    }

    // 5) all waves done reading W -> wlds reusable as store stage
    __syncthreads();

    // 6) feature-half staged stores.  Chunk c = nt*4+kgrp holds features
    //    4c..4c+3 of row row16.  Half h covers chunks h*16..h*16+15
    //    (features h*64..h*64+63).  LDS slot = (c&15) ^ (row&7)  (involution,
    //    bank-uniform on both phases).  4KB per wave.
    float* stg = (float*)wlds + wid * 1024;
    f32x4* ob  = (f32x4*)(out + tile * 2048);
#pragma unroll
    for (int h = 0; h < 2; ++h) {
#pragma unroll
        for (int nt = h * 4; nt < h * 4 + 4; ++nt) {
            int c15 = (nt * 4 + kgrp) & 15;
            *(f32x4*)(stg + row16 * 64 + ((c15 ^ (row16 & 7)) << 2)) = acc[nt];
        }
        asm volatile("s_waitcnt lgkmcnt(0)" ::: "memory");
        __builtin_amdgcn_sched_barrier(0);
        // 4 store instrs: each = 4 rows x 256B (2 full 128B lines per row)
#pragma unroll
        for (int s = 0; s < 4; ++s) {
            int p   = lane + 64 * s;       // 0..255
            int row = p >> 4;              // 0..15
            int c2  = p & 15;
            f32x4 v = *(const f32x4*)(stg + row * 64 + ((c2 ^ (row & 7)) << 2));
            __builtin_nontemporal_store(v, ob + row * 32 + h * 16 + c2);
        }
        // next half's stage writes follow program order; same-wave LDS ops
        // complete in order (r11-proven reuse pattern), fences above guard
        // the read side.
        asm volatile("s_waitcnt lgkmcnt(0)" ::: "memory");
        __builtin_amdgcn_sched_barrier(0);
    }
}

extern "C" void kernel_launch(void* const* d_in, const int* in_sizes, int n_in,
                              void* d_out, int out_size, void* d_ws, size_t ws_size,
                              hipStream_t stream) {
    const float* x      = (const float*)d_in[0];   // [262144,128] fp32
    const float* weight = (const float*)d_in[1];   // [32,32,4] fp32
    const float* bias   = (const float*)d_in[2];   // [128] fp32
    float*       out    = (float*)d_out;           // [262144,128] fp32
    ushort*      wfrag  = (ushort*)d_ws;           // 32 KB fragment-ordered W_eff

    prep_wfrag<<<64, 256, 0, stream>>>(weight, wfrag);
    qgemm<<<2048, 512, 0, stream>>>(x, wfrag, bias, out);
}